// Round 9
// baseline (130.198 us; speedup 1.0000x reference)
//
#include <hip/hip_runtime.h>
#include <hip/hip_fp8.h>

#define NROWS 8192
#define DIM   256

typedef float f32x4 __attribute__((ext_vector_type(4)));
typedef long  i64x2 __attribute__((ext_vector_type(2)));

typedef __attribute__((address_space(3))) char lds_char;
typedef __attribute__((address_space(1))) const char glob_char;

#define LOG2E  1.4426950408889634f
#define NEG_HALF_LOG2E (-0.7213475204444817f)

__device__ __forceinline__ int pack4_fp8(float a, float b, float c, float d) {
#if __has_builtin(__builtin_amdgcn_cvt_pk_fp8_f32)
    int pk = __builtin_amdgcn_cvt_pk_fp8_f32(a, b, 0, false);   // bytes 0,1
    pk     = __builtin_amdgcn_cvt_pk_fp8_f32(c, d, pk, true);   // bytes 2,3
    return pk;
#else
    union { unsigned char by[4]; int i; } u;
    u.by[0] = __hip_fp8_e4m3(a).__x;
    u.by[1] = __hip_fp8_e4m3(b).__x;
    u.by[2] = __hip_fp8_e4m3(c).__x;
    u.by[3] = __hip_fp8_e4m3(d).__x;
    return u.i;
#endif
}

// Cast x,y (f32) -> fp8 e4m3 in frag-ready permuted k-order; store pre-scaled
// norms px = -||x||^2*log2e/2 (f32, from unquantized values); zero the output.
// Permutation per 64-k tile: byte pos p = kt*64 + h*16 + s*8 + j holds
// original k = kt*64 + s*32 + h*8 + j. Applied identically to x and y so the
// dot product is unchanged; a 16B LDS entry (h,row) = {kk0 frag, kk1 frag}
// for the 16x16x32 fp8 MFMA (per-lane 8 fp8 = i64), 16B-contiguous in global.
__global__ __launch_bounds__(256) void prep_kernel(
    const float* __restrict__ x, const float* __restrict__ y,
    unsigned char* __restrict__ xb, unsigned char* __restrict__ yb,
    float* __restrict__ px, float* __restrict__ py,
    float* __restrict__ out)
{
    int tid  = threadIdx.x;
    int lane = tid & 63;
    int w    = tid >> 6;
    int row  = blockIdx.x * 4 + w;          // 0 .. 16383
    bool isx = row < NROWS;
    int r    = isx ? row : row - NROWS;
    const float* src = (isx ? x : y) + (size_t)r * DIM;
    float4 v = reinterpret_cast<const float4*>(src)[lane];
    float sq = v.x*v.x + v.y*v.y + v.z*v.z + v.w*v.w;
    #pragma unroll
    for (int off = 32; off; off >>= 1) sq += __shfl_xor(sq, off);

    int pk = pack4_fp8(v.x, v.y, v.z, v.w);
    int k0 = lane * 4;
    int kt = k0 >> 6, q = k0 & 63;
    int s  = q >> 5, hh = (q >> 3) & 3, j0 = q & 7;                 // j0 in {0,4}
    int p0 = (kt << 6) + (hh << 4) + (s << 3) + j0;
    unsigned char* dst = (isx ? xb : yb) + (size_t)r * DIM + p0;
    *reinterpret_cast<int*>(dst) = pk;

    if (lane == 0) (isx ? px : py)[r] = NEG_HALF_LOG2E * sq;
    if (blockIdx.x == 0 && tid == 0) out[0] = 0.0f;
}

// fp8 GEMM, BM=BN=128, BK=64, dbuf 32 KB LDS (~34 KB total) -> 3 blocks/CU
// (launch_bounds(512,6): VGPR<=85), 24 waves/CU, THREE independent barrier
// domains per CU — per R8 counters the limiter is correlated latency stalls
// (all waves of both blocks at the same barrier/drain point: wall 8610 cyc
// vs 2484 cyc MFMA content), so decorrelation via block count, not deeper
// hand-pipelining (R3/R6 falsified). 8 waves as 2x4, wave-tile 64x32,
// acc 4x2 frags, 6 ds_read_b128 + 16 MFMA per K-step. h-major LDS
// ([h:4][row:128][16B] per operand) measured conflict-free (R6/R8).
// px/py in LDS: epilogue stays in the lgkm domain (R4 lesson).
// XCD map: c=b&7, s=b>>3, bm=((s>>6)<<3)|c, bn=s&63 — B (2 MB total) is
// L2-resident per XCD; A panels stream slowly.
__global__ __launch_bounds__(512, 6) void rbf_gemm_kernel(
    const unsigned char* __restrict__ xb, const unsigned char* __restrict__ yb,
    const float* __restrict__ px, const float* __restrict__ py,
    float* __restrict__ out)
{
    __shared__ __align__(16) char smem[33824];
    // [0,16384)      buf0: A 8K + B 8K
    // [16384,32768)  buf1
    // [32768,33280)  pxl: 128 f32
    // [33280,33792)  pyl: 128 f32
    // [33792,33824)  red[8]
    float* pxl = (float*)(smem + 32768);
    float* pyl = (float*)(smem + 33280);
    float* red = (float*)(smem + 33792);

    int tid  = threadIdx.x;
    int lane = tid & 63;
    int wv   = tid >> 6;                // 0..7
    int wm   = wv >> 2;                 // 0..1: 64-row strip
    int wn   = wv & 3;                  // 0..3: 32-col strip
    int b    = blockIdx.x;
    int c    = b & 7;
    int s    = b >> 3;
    int bm   = ((s >> 6) << 3) | c;     // 0..63
    int bn   = s & 63;                  // 0..63
    int h    = lane >> 4;
    int l15  = lane & 15;

    f32x4 acc[4][2];
    #pragma unroll
    for (int m = 0; m < 4; ++m)
        #pragma unroll
        for (int n = 0; n < 2; ++n)
            acc[m][n] = (f32x4){0.f, 0.f, 0.f, 0.f};

    auto stage = [&](int buf, int kt) {             // 2 loads/thread
        char* base = smem + buf * 16384;
        int hh = tid >> 7, row = tid & 127;
        __builtin_amdgcn_global_load_lds(
            (glob_char*)((const char*)xb + (size_t)(bm * 128 + row) * 256 + kt * 64 + hh * 16),
            (lds_char*)(base + tid * 16), 16, 0, 0);
        __builtin_amdgcn_global_load_lds(
            (glob_char*)((const char*)yb + (size_t)(bn * 128 + row) * 256 + kt * 64 + hh * 16),
            (lds_char*)(base + 8192 + tid * 16), 16, 0, 0);
    };

    auto compute = [&](int buf) {
        const char* Ab = smem + buf * 16384;
        const char* Bb = Ab + 8192;
        i64x2 aF[4], bF[2];
        #pragma unroll
        for (int mf = 0; mf < 4; ++mf)
            aF[mf] = *reinterpret_cast<const i64x2*>(
                Ab + h * 2048 + (wm * 64 + mf * 16 + l15) * 16);
        #pragma unroll
        for (int nf = 0; nf < 2; ++nf)
            bF[nf] = *reinterpret_cast<const i64x2*>(
                Bb + h * 2048 + (wn * 32 + nf * 16 + l15) * 16);
        #pragma unroll
        for (int mf = 0; mf < 4; ++mf)
            #pragma unroll
            for (int nf = 0; nf < 2; ++nf) {
                acc[mf][nf] = __builtin_amdgcn_mfma_f32_16x16x32_fp8_fp8(
                    aF[mf][0], bF[nf][0], acc[mf][nf], 0, 0, 0);
                acc[mf][nf] = __builtin_amdgcn_mfma_f32_16x16x32_fp8_fp8(
                    aF[mf][1], bF[nf][1], acc[mf][nf], 0, 0, 0);
            }
    };

    // ---- prologue: px/py -> LDS, stage tile 0 ----
    if (tid < 128) {
        __builtin_amdgcn_global_load_lds(
            (glob_char*)((const char*)(px + bm * 128) + tid * 4),
            (lds_char*)((char*)pxl + tid * 4), 4, 0, 0);
        __builtin_amdgcn_global_load_lds(
            (glob_char*)((const char*)(py + bn * 128) + tid * 4),
            (lds_char*)((char*)pyl + tid * 4), 4, 0, 0);
    }
    stage(0, 0);
    __syncthreads();

    // ---- K-loop: 4 steps, dbuf prefetch ----
    stage(1, 1); compute(0); __syncthreads();
    stage(0, 2); compute(1); __syncthreads();
    stage(1, 3); compute(0); __syncthreads();
    compute(1);                                      // no barrier needed after

    // ---- epilogue: lsum += exp2(fma(dot, log2e, px+py)) ----
    // C/D layout (verified): col = lane&15, row = (lane>>4)*4 + reg
    float lsum = 0.f;
    float py2[2];
    #pragma unroll
    for (int nf = 0; nf < 2; ++nf) py2[nf] = pyl[wn * 32 + nf * 16 + l15];
    #pragma unroll
    for (int mf = 0; mf < 4; ++mf) {
        f32x4 pxv = *reinterpret_cast<const f32x4*>(pxl + wm * 64 + mf * 16 + h * 4);
        #pragma unroll
        for (int r = 0; r < 4; ++r) {
            float pv = pxv[r];
            #pragma unroll
            for (int nf = 0; nf < 2; ++nf)
                lsum += exp2f(fmaf(acc[mf][nf][r], LOG2E, pv + py2[nf]));
        }
    }
    #pragma unroll
    for (int off = 32; off; off >>= 1) lsum += __shfl_xor(lsum, off);
    if (lane == 0) red[wv] = lsum;
    __syncthreads();
    if (tid == 0) {
        float ss = (red[0] + red[1] + red[2] + red[3] +
                    red[4] + red[5] + red[6] + red[7]) * 1.4901161193847656e-08f;
        atomicAdd(out, ss);
    }
}

extern "C" void kernel_launch(void* const* d_in, const int* in_sizes, int n_in,
                              void* d_out, int out_size, void* d_ws, size_t ws_size,
                              hipStream_t stream) {
    const float* x = (const float*)d_in[0];
    const float* y = (const float*)d_in[1];
    float* out = (float*)d_out;
    char* ws = (char*)d_ws;
    unsigned char* xb = (unsigned char*)ws;                         // 2 MiB
    unsigned char* yb = (unsigned char*)(ws + (size_t)2 * 1024 * 1024);
    float* px = (float*)(ws + (size_t)4 * 1024 * 1024);             // 32 KiB
    float* py = (float*)(ws + (size_t)4 * 1024 * 1024 + 32 * 1024);

    hipLaunchKernelGGL(prep_kernel, dim3(4096), dim3(256), 0, stream,
                       x, y, xb, yb, px, py, out);
    hipLaunchKernelGGL(rbf_gemm_kernel, dim3(4096), dim3(512), 0, stream,
                       xb, yb, px, py, out);
}

// Round 11
// 127.274 us; speedup vs baseline: 1.0230x; 1.0230x over previous
//
#include <hip/hip_runtime.h>
#include <hip/hip_fp8.h>

#define NROWS 8192
#define DIM   256

typedef float f32x4 __attribute__((ext_vector_type(4)));
typedef int   i32x4 __attribute__((ext_vector_type(4)));
typedef int   i32x8 __attribute__((ext_vector_type(8)));

typedef __attribute__((address_space(3))) char lds_char;
typedef __attribute__((address_space(1))) const char glob_char;

#define LOG2E  1.4426950408889634f
#define NEG_HALF_LOG2E (-0.7213475204444817f)
#define UNIT_SCALE 0x7F7F7F7F   // E8M0 127 = 2^0 in all 4 bytes

__device__ __forceinline__ int pack4_fp8(float a, float b, float c, float d) {
#if __has_builtin(__builtin_amdgcn_cvt_pk_fp8_f32)
    int pk = __builtin_amdgcn_cvt_pk_fp8_f32(a, b, 0, false);   // bytes 0,1
    pk     = __builtin_amdgcn_cvt_pk_fp8_f32(c, d, pk, true);   // bytes 2,3
    return pk;
#else
    union { unsigned char by[4]; int i; } u;
    u.by[0] = __hip_fp8_e4m3(a).__x;
    u.by[1] = __hip_fp8_e4m3(b).__x;
    u.by[2] = __hip_fp8_e4m3(c).__x;
    u.by[3] = __hip_fp8_e4m3(d).__x;
    return u.i;
#endif
}

// Cast x,y (f32) -> fp8 e4m3 in MX-frag-ready permuted k-order; store
// pre-scaled norms px = -||x||^2*log2e/2; zero the output.
// For mfma_scale 16x16x128, lane group h = lane>>4 holds k = h*32 + [0,32)
// of each 128-k tile (32 B = VGPR bytes j = j2*16 + b). Permutation within
// a 128-k tile: byte pos P = j2*64 + h*16 + b holds original
// k = h*32 + j2*16 + b. Applied identically to x and y -> dot invariant
// even if the assumed HW k-map is permuted (A/B maps are symmetric).
__global__ __launch_bounds__(256) void prep_kernel(
    const float* __restrict__ x, const float* __restrict__ y,
    unsigned char* __restrict__ xb, unsigned char* __restrict__ yb,
    float* __restrict__ px, float* __restrict__ py,
    float* __restrict__ out)
{
    int tid  = threadIdx.x;
    int lane = tid & 63;
    int w    = tid >> 6;
    int row  = blockIdx.x * 4 + w;          // 0 .. 16383
    bool isx = row < NROWS;
    int r    = isx ? row : row - NROWS;
    const float* src = (isx ? x : y) + (size_t)r * DIM;
    float4 v = reinterpret_cast<const float4*>(src)[lane];
    float sq = v.x*v.x + v.y*v.y + v.z*v.z + v.w*v.w;
    #pragma unroll
    for (int off = 32; off; off >>= 1) sq += __shfl_xor(sq, off);

    int pk = pack4_fp8(v.x, v.y, v.z, v.w);
    int k0 = lane * 4;
    int kt = k0 >> 7;                       // 128-k tile
    int h  = (k0 >> 5) & 3;
    int j2 = (k0 >> 4) & 1;
    int b0 = k0 & 15;                       // in {0,4,8,12} -> int store stays in-entry
    int p0 = kt * 128 + j2 * 64 + h * 16 + b0;
    unsigned char* dst = (isx ? xb : yb) + (size_t)r * DIM + p0;
    *reinterpret_cast<int*>(dst) = pk;

    if (lane == 0) (isx ? px : py)[r] = NEG_HALF_LOG2E * sq;
    if (blockIdx.x == 0 && tid == 0) out[0] = 0.0f;
}

// MX-fp8 GEMM via mfma_scale_f32_16x16x128_f8f6f4 (unit E8M0 scales):
// K=128 per instruction -> 1/4 the MFMA instructions and sync points of
// the 16x16x32 path (R8). R8 shell otherwise: BM=BN=128, 8 waves (2x4),
// wave-tile 64x32, dbuf 64 KB (2 blocks/CU at launch_bounds(512,4)),
// 2-phase syncthreads. LDS per operand per K-tile: [j2*4+h : 8][row:128][16B]
// (16 KB); frag = 2x ds_read_b128 (j2=0,1) -> v8i32. 16-lane h-groups read
// rows at stride 16 B = 2-way bank aliasing (free, verified R6/R8).
// acc f32x4 per frag, C/D layout = 16x16 shape (dtype-independent, §3).
// px/py in LDS (lgkm-domain epilogue). XCD map: c=b&7, bm=c*8+(b>>9),
// bn=(b>>3)&63 — per-XCD set = A 256 KB + B 2 MB, L2-resident.
__global__ __launch_bounds__(512, 4) void rbf_gemm_kernel(
    const unsigned char* __restrict__ xb, const unsigned char* __restrict__ yb,
    const float* __restrict__ px, const float* __restrict__ py,
    float* __restrict__ out)
{
    __shared__ __align__(16) char smem[66592];
    // [0,32768)      buf0: A 16K + B 16K
    // [32768,65536)  buf1
    // [65536,66048)  pxl: 128 f32
    // [66048,66560)  pyl: 128 f32
    // [66560,66592)  red[8]
    float* pxl = (float*)(smem + 65536);
    float* pyl = (float*)(smem + 66048);
    float* red = (float*)(smem + 66560);

    int tid  = threadIdx.x;
    int lane = tid & 63;
    int wv   = tid >> 6;                // 0..7
    int wm   = wv >> 2;                 // 0..1: 64-row strip
    int wn   = wv & 3;                  // 0..3: 32-col strip
    int b    = blockIdx.x;
    int bm   = (b & 7) * 8 + (b >> 9);  // 0..63
    int bn   = (b >> 3) & 63;           // 0..63
    int h    = lane >> 4;
    int l15  = lane & 15;

    f32x4 acc[4][2];
    #pragma unroll
    for (int m = 0; m < 4; ++m)
        #pragma unroll
        for (int n = 0; n < 2; ++n)
            acc[m][n] = (f32x4){0.f, 0.f, 0.f, 0.f};

    auto stage = [&](int buf, int kt) {             // 4 loads/thread
        char* base = smem + buf * 32768;
        #pragma unroll
        for (int j = 0; j < 2; ++j) {
            int e = j * 512 + tid;                  // 0..1023
            int j2h = e >> 7, row = e & 127;
            __builtin_amdgcn_global_load_lds(
                (glob_char*)((const char*)xb + (size_t)(bm * 128 + row) * 256 + kt * 128 + j2h * 16),
                (lds_char*)(base + e * 16), 16, 0, 0);
            __builtin_amdgcn_global_load_lds(
                (glob_char*)((const char*)yb + (size_t)(bn * 128 + row) * 256 + kt * 128 + j2h * 16),
                (lds_char*)(base + 16384 + e * 16), 16, 0, 0);
        }
    };

    auto compute = [&](int buf) {
        const char* Ab = smem + buf * 32768;
        const char* Bb = Ab + 16384;
        i32x8 aF[4], bF[2];
        #pragma unroll
        for (int mf = 0; mf < 4; ++mf) {
            int row = wm * 64 + mf * 16 + l15;
            i32x4 r0 = *reinterpret_cast<const i32x4*>(Ab + (0 + h) * 2048 + row * 16);
            i32x4 r1 = *reinterpret_cast<const i32x4*>(Ab + (4 + h) * 2048 + row * 16);
            aF[mf] = __builtin_shufflevector(r0, r1, 0, 1, 2, 3, 4, 5, 6, 7);
        }
        #pragma unroll
        for (int nf = 0; nf < 2; ++nf) {
            int row = wn * 32 + nf * 16 + l15;
            i32x4 r0 = *reinterpret_cast<const i32x4*>(Bb + (0 + h) * 2048 + row * 16);
            i32x4 r1 = *reinterpret_cast<const i32x4*>(Bb + (4 + h) * 2048 + row * 16);
            bF[nf] = __builtin_shufflevector(r0, r1, 0, 1, 2, 3, 4, 5, 6, 7);
        }
        #pragma unroll
        for (int mf = 0; mf < 4; ++mf)
            #pragma unroll
            for (int nf = 0; nf < 2; ++nf)
                acc[mf][nf] = __builtin_amdgcn_mfma_scale_f32_16x16x128_f8f6f4(
                    aF[mf], bF[nf], acc[mf][nf],
                    0, 0,                       // cbsz=fp8(e4m3), blgp=fp8(e4m3)
                    0, UNIT_SCALE,              // opsel_a, scale_a
                    0, UNIT_SCALE);             // opsel_b, scale_b
    };

    // ---- prologue: px/py -> LDS, stage tile 0 ----
    if (tid < 128) {
        __builtin_amdgcn_global_load_lds(
            (glob_char*)((const char*)(px + bm * 128) + tid * 4),
            (lds_char*)((char*)pxl + tid * 4), 4, 0, 0);
        __builtin_amdgcn_global_load_lds(
            (glob_char*)((const char*)(py + bn * 128) + tid * 4),
            (lds_char*)((char*)pyl + tid * 4), 4, 0, 0);
    }
    stage(0, 0);
    __syncthreads();

    // ---- K-loop: 2 K-tiles of 128 ----
    stage(1, 1);
    compute(0);
    __syncthreads();
    compute(1);

    // ---- epilogue: lsum += exp2(fma(dot, log2e, px+py)) ----
    // C/D layout (16x16 shape, dtype-independent): col=lane&15, row=(lane>>4)*4+reg
    float lsum = 0.f;
    float py2[2];
    #pragma unroll
    for (int nf = 0; nf < 2; ++nf) py2[nf] = pyl[wn * 32 + nf * 16 + l15];
    #pragma unroll
    for (int mf = 0; mf < 4; ++mf) {
        f32x4 pxv = *reinterpret_cast<const f32x4*>(pxl + wm * 64 + mf * 16 + h * 4);
        #pragma unroll
        for (int r = 0; r < 4; ++r) {
            float pv = pxv[r];
            #pragma unroll
            for (int nf = 0; nf < 2; ++nf)
                lsum += exp2f(fmaf(acc[mf][nf][r], LOG2E, pv + py2[nf]));
        }
    }
    #pragma unroll
    for (int off = 32; off; off >>= 1) lsum += __shfl_xor(lsum, off);
    if (lane == 0) red[wv] = lsum;
    __syncthreads();
    if (tid == 0) {
        float ss = (red[0] + red[1] + red[2] + red[3] +
                    red[4] + red[5] + red[6] + red[7]) * 1.4901161193847656e-08f;
        atomicAdd(out, ss);
    }
}

extern "C" void kernel_launch(void* const* d_in, const int* in_sizes, int n_in,
                              void* d_out, int out_size, void* d_ws, size_t ws_size,
                              hipStream_t stream) {
    const float* x = (const float*)d_in[0];
    const float* y = (const float*)d_in[1];
    float* out = (float*)d_out;
    char* ws = (char*)d_ws;
    unsigned char* xb = (unsigned char*)ws;                         // 2 MiB
    unsigned char* yb = (unsigned char*)(ws + (size_t)2 * 1024 * 1024);
    float* px = (float*)(ws + (size_t)4 * 1024 * 1024);             // 32 KiB
    float* py = (float*)(ws + (size_t)4 * 1024 * 1024 + 32 * 1024);

    hipLaunchKernelGGL(prep_kernel, dim3(4096), dim3(256), 0, stream,
                       x, y, xb, yb, px, py, out);
    hipLaunchKernelGGL(rbf_gemm_kernel, dim3(4096), dim3(512), 0, stream,
                       xb, yb, px, py, out);
}